// Round 1
// baseline (252.713 us; speedup 1.0000x reference)
//
#include <hip/hip_runtime.h>

// BilateralSlice: grid [N=4, gh=16, gw=16, gd=8, C=12] f32, guide [4,1024,1024] f32
// out [4,1024,1024,12] f32.
// One thread per pixel; 12 channels accumulated in 3 float4 registers.

#define GH 16
#define GW 16
#define GD 8
#define NC 12
#define IMH 1024
#define IMW 1024
#define NBATCH 4

__device__ __forceinline__ void fma4(float4& a, float w, const float4& v) {
    a.x = fmaf(w, v.x, a.x);
    a.y = fmaf(w, v.y, a.y);
    a.z = fmaf(w, v.z, a.z);
    a.w = fmaf(w, v.w, a.w);
}

__global__ __launch_bounds__(256) void bilateral_slice_kernel(
    const float* __restrict__ grid,
    const float* __restrict__ guide,
    float* __restrict__ out)
{
    const int idx = blockIdx.x * 256 + threadIdx.x;   // flat pixel index, exact grid
    const int x = idx & (IMW - 1);
    const int y = (idx >> 10) & (IMH - 1);
    const int n = idx >> 20;

    const float gx = (x + 0.5f) * ((float)GW / (float)IMW);
    const float gy = (y + 0.5f) * ((float)GH / (float)IMH);
    const float gz = guide[idx] * (float)GD;

    const float fx = floorf(gx - 0.5f);
    const float fy = floorf(gy - 0.5f);
    const float fz = floorf(gz - 0.5f);

    float wx[2], wy[2], wz[2];
    int cx[2], cy[2], cz[2];
#pragma unroll
    for (int i = 0; i < 2; ++i) {
        const float xx = fx + (float)i;
        const float yy = fy + (float)i;
        const float zz = fz + (float)i;
        wx[i] = fmaxf(1.0f - fabsf(xx + 0.5f - gx), 0.0f);
        wy[i] = fmaxf(1.0f - fabsf(yy + 0.5f - gy), 0.0f);
        wz[i] = fmaxf(1.0f - fabsf(zz + 0.5f - gz), 0.0f);
        cx[i] = min(max((int)xx, 0), GW - 1);
        cy[i] = min(max((int)yy, 0), GH - 1);
        cz[i] = min(max((int)zz, 0), GD - 1);
    }

    float4 a0 = make_float4(0.f, 0.f, 0.f, 0.f);
    float4 a1 = make_float4(0.f, 0.f, 0.f, 0.f);
    float4 a2 = make_float4(0.f, 0.f, 0.f, 0.f);

    const float* gbase = grid + (size_t)n * (GH * GW * GD * NC);
#pragma unroll
    for (int j = 0; j < 2; ++j) {
#pragma unroll
        for (int i = 0; i < 2; ++i) {
            const float wxy = wy[j] * wx[i];
            const float* gp = gbase + (cy[j] * GW + cx[i]) * (GD * NC);
#pragma unroll
            for (int k = 0; k < 2; ++k) {
                const float w = wxy * wz[k];
                const float4* g4 = (const float4*)(gp + cz[k] * NC);
                const float4 v0 = g4[0];
                const float4 v1 = g4[1];
                const float4 v2 = g4[2];
                fma4(a0, w, v0);
                fma4(a1, w, v1);
                fma4(a2, w, v2);
            }
        }
    }

    float4* o = (float4*)(out + (size_t)idx * NC);
    o[0] = a0;
    o[1] = a1;
    o[2] = a2;
}

extern "C" void kernel_launch(void* const* d_in, const int* in_sizes, int n_in,
                              void* d_out, int out_size, void* d_ws, size_t ws_size,
                              hipStream_t stream) {
    const float* grid  = (const float*)d_in[0];
    const float* guide = (const float*)d_in[1];
    float* out = (float*)d_out;

    const int total_pixels = NBATCH * IMH * IMW;     // 4,194,304
    const int block = 256;
    const int nblocks = total_pixels / block;        // 16384, exact

    bilateral_slice_kernel<<<nblocks, block, 0, stream>>>(grid, guide, out);
}

// Round 3
// 248.533 us; speedup vs baseline: 1.0168x; 1.0168x over previous
//
#include <hip/hip_runtime.h>

// BilateralSlice: grid [N=4, gh=16, gw=16, gd=8, C=12] f32, guide [4,1024,1024] f32
// out [4,1024,1024,12] f32.
// One thread per pixel computes 12 channels; output staged through LDS so
// global stores are perfectly dense (16 B/lane contiguous).

#define GH 16
#define GW 16
#define GD 8
#define NC 12
#define IMH 1024
#define IMW 1024
#define NBATCH 4

__device__ __forceinline__ void fma4(float4& a, float w, const float4& v) {
    a.x = fmaf(w, v.x, a.x);
    a.y = fmaf(w, v.y, a.y);
    a.z = fmaf(w, v.z, a.z);
    a.w = fmaf(w, v.w, a.w);
}

__global__ __launch_bounds__(256) void bilateral_slice_kernel(
    const float* __restrict__ grid,
    const float* __restrict__ guide,
    float* __restrict__ out)
{
    __shared__ float4 lds4[3 * 256];          // SoA by part: [part][local_pixel], 12 KB

    const int t = threadIdx.x;
    const int idx = blockIdx.x * 256 + t;     // flat pixel index, exact grid
    const int x = idx & (IMW - 1);
    const int y = (idx >> 10) & (IMH - 1);
    const int n = idx >> 20;

    const float gx = (x + 0.5f) * ((float)GW / (float)IMW);
    const float gy = (y + 0.5f) * ((float)GH / (float)IMH);
    const float gz = guide[idx] * (float)GD;

    const float fx = floorf(gx - 0.5f);
    const float fy = floorf(gy - 0.5f);
    const float fz = floorf(gz - 0.5f);

    float wx[2], wy[2], wz[2];
    int cx[2], cy[2], cz[2];
#pragma unroll
    for (int i = 0; i < 2; ++i) {
        const float xx = fx + (float)i;
        const float yy = fy + (float)i;
        const float zz = fz + (float)i;
        wx[i] = fmaxf(1.0f - fabsf(xx + 0.5f - gx), 0.0f);
        wy[i] = fmaxf(1.0f - fabsf(yy + 0.5f - gy), 0.0f);
        wz[i] = fmaxf(1.0f - fabsf(zz + 0.5f - gz), 0.0f);
        cx[i] = min(max((int)xx, 0), GW - 1);
        cy[i] = min(max((int)yy, 0), GH - 1);
        cz[i] = min(max((int)zz, 0), GD - 1);
    }

    float4 a0 = make_float4(0.f, 0.f, 0.f, 0.f);
    float4 a1 = make_float4(0.f, 0.f, 0.f, 0.f);
    float4 a2 = make_float4(0.f, 0.f, 0.f, 0.f);

    const float* gbase = grid + (size_t)n * (GH * GW * GD * NC);
#pragma unroll
    for (int j = 0; j < 2; ++j) {
#pragma unroll
        for (int i = 0; i < 2; ++i) {
            const float wxy = wy[j] * wx[i];
            const float* gp = gbase + (cy[j] * GW + cx[i]) * (GD * NC);
#pragma unroll
            for (int k = 0; k < 2; ++k) {
                const float w = wxy * wz[k];
                const float4* g4 = (const float4*)(gp + cz[k] * NC);
                const float4 v0 = g4[0];
                const float4 v1 = g4[1];
                const float4 v2 = g4[2];
                fma4(a0, w, v0);
                fma4(a1, w, v1);
                fma4(a2, w, v2);
            }
        }
    }

    // Stage to LDS (conflict-free: 16 B/lane contiguous per instruction).
    lds4[0 * 256 + t] = a0;
    lds4[1 * 256 + t] = a1;
    lds4[2 * 256 + t] = a2;
    __syncthreads();

    // Dense block-contiguous output: this block owns 768 float4s.
    float4* __restrict__ out4 = (float4*)out + (size_t)blockIdx.x * 768;
#pragma unroll
    for (int s = 0; s < 3; ++s) {
        const int e = s * 256 + t;            // flat float4 index within block
        const int p = e / 3;                  // local pixel (magic-mul by compiler)
        const int part = e - 3 * p;           // which float4 of that pixel
        out4[e] = lds4[part * 256 + p];
    }
}

extern "C" void kernel_launch(void* const* d_in, const int* in_sizes, int n_in,
                              void* d_out, int out_size, void* d_ws, size_t ws_size,
                              hipStream_t stream) {
    const float* grid  = (const float*)d_in[0];
    const float* guide = (const float*)d_in[1];
    float* out = (float*)d_out;

    const int total_pixels = NBATCH * IMH * IMW;     // 4,194,304
    const int block = 256;
    const int nblocks = total_pixels / block;        // 16384, exact

    bilateral_slice_kernel<<<nblocks, block, 0, stream>>>(grid, guide, out);
}